// Round 4
// baseline (88.904 us; speedup 1.0000x reference)
//
#include <hip/hip_runtime.h>

// Problem constants (fixed by the reference).
#define NS 4
#define NA 8192
#define NTOK 1024
#define NC 8
#define THREADS 256
#define JSLOTS 4
#define JPB (THREADS * JSLOTS)   // 1024 j-atoms per block (= one chain)
#define TI 64                    // i-atoms per block
#define TPJ (JPB / TI)           // 16 i-tiles per j-tile
// Strict-triangle grid: only blocks with i-tile entirely before the j-tile's
// chain. Active blocks per sample = sum_{jb=1..7} jb*16 = 448. Diagonal
// (same-chain) tiles only feed the masked counts[a][a] -> never scheduled.
#define GRIDX 448
#define NBLOCKS (GRIDX * NS)     // 1792 = exactly 7 blocks/CU, all co-resident

// Session ledger:
//  R11 (reverted): per-block __threadfence() + ticket = ~90us regression --
//    agent-scope fences emit buffer_wbl2/inv per block (XCD L2s non-coherent).
//    pk_fma packing also regressed (per-t VGPR broadcasts of i-operands).
//  R13 (kept, neutral): setup kernel deleted; counts zeroed by 1KiB memset
//    node; chain ids + coord transform computed in the clash prologue.
//  R14 (this): finalize merged into clash via waitcnt-ordered ticket --
//    NO fences. counts atomics are device-scope relaxed RMWs (coherent
//    point); s_waitcnt vmcnt(0) orders them before the ticket; last block
//    reads counts via atomicAdd(p,0) RMWs (stale-L2-proof). Saves one
//    launch + graph gap.

// ws layout:
//   counts[256] int : global accumulators   (zeroed by memset node)
//   counts[256] = done ticket               (zeroed by memset node)

// Ballot/popc accumulation (best measured form, R9): per (t,u) 4 VALU
// (3 fma + v_cmp->sgpr) + 2 SALU (s_bcnt1 + s_add), balanced across the
// vector and scalar pipes. Block LDS reduction red[] -> <=64 global atomics
// per block (per-wave global atomics were a 4.5x regression in R8;
// vcc-serialized v_addc asm regressed in R10).
__global__ __launch_bounds__(THREADS, 7)
void clash_kernel(const float* __restrict__ coords, const int* __restrict__ asym,
                  const int* __restrict__ a2t, int* __restrict__ counts,
                  float* __restrict__ out) {
  __shared__ int red[NC * NC];
  __shared__ float4 itile[TI];
  __shared__ int hist[NC];
  __shared__ int lastFlag;

  const int tid = threadIdx.x;
  const int s = blockIdx.z;
  const float TWO_THR2 = 2.42f;  // 2*1.1^2
  int* done = counts + NS * NC * NC;  // ticket at counts[256]

  // Decode strict-triangle block index. cum(jb) = 8*jb*(jb-1) blocks precede
  // j-tile jb; jb ranges 1..7, ib in [0, jb*16).
  int f = blockIdx.x, jb = 1;
  while (f >= 8 * jb * (jb + 1)) ++jb;
  const int ib = f - 8 * jb * (jb - 1);

  if (tid < NC * NC) red[tid] = 0;

  const float* __restrict__ cb = coords + (size_t)s * NA * 3;

  // Per-thread j-atoms (4 slots): transform on the fly.
  // xj = 2x, yj = 2y, zj = 2z, tj2 = 2*sq_j  (identical algebra to staged).
  float xj[JSLOTS], yj[JSLOTS], zj[JSLOTS], tj2[JSLOTS];
  int bj[JSLOTS];
#pragma unroll
  for (int u = 0; u < JSLOTS; ++u) {
    int j = jb * JPB + u * THREADS + tid;
    float x = cb[3 * j + 0], y = cb[3 * j + 1], z = cb[3 * j + 2];
    xj[u] = x + x; yj[u] = y + y; zj[u] = z + z;
    float sq = fmaf(x, x, fmaf(y, y, z * z));
    tj2[u] = sq + sq;
    bj[u] = asym[a2t[j]];
  }

  // i-tile transform, once per block into LDS: (2x, 2y, 2z, 2*(thr2-sq)).
  if (tid < TI) {
    int i = ib * TI + tid;
    float x = cb[3 * i + 0], y = cb[3 * i + 1], z = cb[3 * i + 2];
    float sq = fmaf(x, x, fmaf(y, y, z * z));
    itile[tid] = make_float4(x + x, y + y, z + z, TWO_THR2 - (sq + sq));
  }

  // i-tile chain id + uniformity: per-lane gather + wave votes (no LDS).
  int myi = asym[a2t[ib * TI + (tid & 63)]];
  const int A = __builtin_amdgcn_readfirstlane(myi);
  bool uniform = __all(myi == A);

  int b0[JSLOTS];
#pragma unroll
  for (int u = 0; u < JSLOTS; ++u) {
    b0[u] = __builtin_amdgcn_readfirstlane(bj[u]);
    uniform = uniform && __all(bj[u] == b0[u]);
  }

  __syncthreads();  // red[] init + itile[] visible to all waves

  // clash <=> (2xi)(2xj)+(2yi)(2yj)+(2zi)(2zj) + 2*(thr2-sq_i) > 2*sq_j
  if (uniform) {
    int acc[JSLOTS] = {0, 0, 0, 0};
#pragma unroll 8
    for (int t = 0; t < TI; ++t) {
      float4 ci = itile[t];  // wave-uniform addr -> broadcast ds_read_b128
#pragma unroll
      for (int u = 0; u < JSLOTS; ++u) {
        float d = fmaf(ci.x, xj[u], fmaf(ci.y, yj[u], fmaf(ci.z, zj[u], ci.w)));
        acc[u] += __popcll(__ballot(d > tj2[u]));  // v_cmp + s_bcnt1 + s_add
      }
    }
    if ((tid & 63) == 0) {
#pragma unroll
      for (int u = 0; u < JSLOTS; ++u) {
        if (acc[u]) {
          atomicAdd(&red[A * NC + b0[u]], acc[u]);
          atomicAdd(&red[b0[u] * NC + A], acc[u]);  // strict blocks: mirror
        }
      }
    }
  } else {
    // robustness path (not hit with this data layout)
    for (int t = 0; t < TI; ++t) {
      float4 ci = itile[t];
      int a = asym[a2t[ib * TI + t]];
#pragma unroll
      for (int u = 0; u < JSLOTS; ++u) {
        float d = fmaf(ci.x, xj[u], fmaf(ci.y, yj[u], fmaf(ci.z, zj[u], ci.w)));
        if (d > tj2[u]) {
          atomicAdd(&red[a * NC + bj[u]], 1);
          atomicAdd(&red[bj[u] * NC + a], 1);
        }
      }
    }
  }

  __syncthreads();
  // Flush block-local counts: device-scope relaxed atomics (no cache ops).
  if (tid < NC * NC) {
    int v = red[tid];
    if (v) atomicAdd(&counts[s * NC * NC + tid], v);
  }

  // ---- merged finalize: waitcnt-ordered ticket, NO fences ----
  // Wait for this wave's count atomics to reach the coherent point before
  // taking a ticket. Pure s_waitcnt: no buffer_wbl2/inv (the R11 poison).
  asm volatile("s_waitcnt vmcnt(0)" ::: "memory");
  if (tid == 0) lastFlag = (atomicAdd(done, 1) == NBLOCKS - 1);
  __syncthreads();
  if (!lastFlag) return;

  // Last block: every other block's counts-adds were acked before its
  // ticket, so counts is complete. Read via atomic RMW (coherent point,
  // immune to stale per-XCD L2 lines). asym is host-written input: plain.
  if (tid < NC) hist[tid] = 0;
  __syncthreads();
  for (int t = tid; t < NTOK; t += THREADS) atomicAdd(&hist[asym[t]], NA / NTOK);
  __syncthreads();

  int c = atomicAdd(&counts[tid], 0);  // tid = s*64 + a*8 + b
  int a = (tid >> 3) & 7, b = tid & 7;
  float total = (a == b) ? 0.0f : (float)c;
  float minn = (float)min(hist[a], hist[b]);
  float rel = total / minn;
  out[tid] = ((total > 100.0f) || (rel > 0.5f)) ? 1.0f : 0.0f;
  out[256 + 2 * tid + 0] = total;
  out[256 + 2 * tid + 1] = rel;
}

extern "C" void kernel_launch(void* const* d_in, const int* in_sizes, int n_in,
                              void* d_out, int out_size, void* d_ws, size_t ws_size,
                              hipStream_t stream) {
  const float* coords = (const float*)d_in[0];  // [4, 8192, 3] f32
  const int* asym = (const int*)d_in[1];        // [1024] i32
  const int* a2t = (const int*)d_in[2];         // [8192] i32
  float* out = (float*)d_out;                   // 256 flags + 512 details

  int* counts = (int*)d_ws;                     // [256 counts + 1 ticket]

  hipMemsetAsync(counts, 0, (NS * NC * NC + 1) * sizeof(int), stream);
  clash_kernel<<<dim3(GRIDX, 1, NS), THREADS, 0, stream>>>(coords, asym, a2t,
                                                           counts, out);
}

// Round 5
// 77.523 us; speedup vs baseline: 1.1468x; 1.1468x over previous
//
#include <hip/hip_runtime.h>

// Problem constants (fixed by the reference).
#define NS 4
#define NA 8192
#define NTOK 1024
#define NC 8
#define THREADS 256
#define JSLOTS 4
#define JPB (THREADS * JSLOTS)   // 1024 j-atoms per block (= one chain)
#define TI 64                    // i-atoms per block
#define TPJ (JPB / TI)           // 16 i-tiles per j-tile
// Strict-triangle grid: only blocks with i-tile entirely before the j-tile's
// chain. Active blocks per sample = sum_{jb=1..7} jb*16 = 448. Diagonal
// (same-chain) tiles only feed the masked counts[a][a] -> never scheduled.
#define GRIDX 448

// Session ledger (all measured):
//  R8  per-wave global atomics ............ 4.5x regression
//  R10 vcc-serialized v_addc inline asm ... regression
//  R11 __threadfence()+ticket merge ....... +92us (buffer_wbl2/inv per block,
//      XCD L2s non-coherent); pk_fma packing also regressed (per-t VGPR
//      broadcasts of wave-uniform i-operands)
//  R13 setup kernel -> memset node + in-kernel transform: NEUTRAL (kept,
//      simpler; node weight below a few us doesn't matter, node count does)
//  R14 fence-FREE ticket merge (s_waitcnt-ordered) ... +11us: the single-line
//      ticket RMW burst + per-block vmcnt(0) ack wait serialize at the
//      coherent point. Last-block merge is dead BOTH ways; separate finalize
//      launch is strictly cheaper than any in-kernel device rendezvous.
//  Budget at 77.6us: ~40us harness ws re-poison fill (84% HBM peak, fixed),
//  ~23us clash, ~10-14us launches/gaps. Clash has no top-5 counters; blind
//  inner-loop edits are 0/5 -- R9 ballot/popc form is final.

// ws layout:
//   counts[NS*NC*NC] int : global accumulators (zeroed by memset node)

// Ballot/popc accumulation (best measured form, R9): per (t,u) 4 VALU
// (3 fma + v_cmp->sgpr) + 2 SALU (s_bcnt1 + s_add), balanced across the
// vector and scalar pipes. Block LDS reduction red[] -> <=64 global atomics
// per block.
__global__ __launch_bounds__(THREADS, 7)
void clash_kernel(const float* __restrict__ coords, const int* __restrict__ asym,
                  const int* __restrict__ a2t, int* __restrict__ counts) {
  __shared__ int red[NC * NC];
  __shared__ float4 itile[TI];

  const int tid = threadIdx.x;
  const int s = blockIdx.z;
  const float TWO_THR2 = 2.42f;  // 2*1.1^2

  // Decode strict-triangle block index. cum(jb) = 8*jb*(jb-1) blocks precede
  // j-tile jb; jb ranges 1..7, ib in [0, jb*16).
  int f = blockIdx.x, jb = 1;
  while (f >= 8 * jb * (jb + 1)) ++jb;
  const int ib = f - 8 * jb * (jb - 1);

  if (tid < NC * NC) red[tid] = 0;

  const float* __restrict__ cb = coords + (size_t)s * NA * 3;

  // Per-thread j-atoms (4 slots): transform on the fly.
  // xj = 2x, yj = 2y, zj = 2z, tj2 = 2*sq_j  (identical algebra to staged).
  float xj[JSLOTS], yj[JSLOTS], zj[JSLOTS], tj2[JSLOTS];
  int bj[JSLOTS];
#pragma unroll
  for (int u = 0; u < JSLOTS; ++u) {
    int j = jb * JPB + u * THREADS + tid;
    float x = cb[3 * j + 0], y = cb[3 * j + 1], z = cb[3 * j + 2];
    xj[u] = x + x; yj[u] = y + y; zj[u] = z + z;
    float sq = fmaf(x, x, fmaf(y, y, z * z));
    tj2[u] = sq + sq;
    bj[u] = asym[a2t[j]];
  }

  // i-tile transform, once per block into LDS: (2x, 2y, 2z, 2*(thr2-sq)).
  if (tid < TI) {
    int i = ib * TI + tid;
    float x = cb[3 * i + 0], y = cb[3 * i + 1], z = cb[3 * i + 2];
    float sq = fmaf(x, x, fmaf(y, y, z * z));
    itile[tid] = make_float4(x + x, y + y, z + z, TWO_THR2 - (sq + sq));
  }

  // i-tile chain id + uniformity: per-lane gather + wave votes (no LDS).
  int myi = asym[a2t[ib * TI + (tid & 63)]];
  const int A = __builtin_amdgcn_readfirstlane(myi);
  bool uniform = __all(myi == A);

  int b0[JSLOTS];
#pragma unroll
  for (int u = 0; u < JSLOTS; ++u) {
    b0[u] = __builtin_amdgcn_readfirstlane(bj[u]);
    uniform = uniform && __all(bj[u] == b0[u]);
  }

  __syncthreads();  // red[] init + itile[] visible to all waves

  // clash <=> (2xi)(2xj)+(2yi)(2yj)+(2zi)(2zj) + 2*(thr2-sq_i) > 2*sq_j
  if (uniform) {
    int acc[JSLOTS] = {0, 0, 0, 0};
#pragma unroll 8
    for (int t = 0; t < TI; ++t) {
      float4 ci = itile[t];  // wave-uniform addr -> broadcast ds_read_b128
#pragma unroll
      for (int u = 0; u < JSLOTS; ++u) {
        float d = fmaf(ci.x, xj[u], fmaf(ci.y, yj[u], fmaf(ci.z, zj[u], ci.w)));
        acc[u] += __popcll(__ballot(d > tj2[u]));  // v_cmp + s_bcnt1 + s_add
      }
    }
    if ((tid & 63) == 0) {
#pragma unroll
      for (int u = 0; u < JSLOTS; ++u) {
        if (acc[u]) {
          atomicAdd(&red[A * NC + b0[u]], acc[u]);
          atomicAdd(&red[b0[u] * NC + A], acc[u]);  // strict blocks: mirror
        }
      }
    }
  } else {
    // robustness path (not hit with this data layout)
    for (int t = 0; t < TI; ++t) {
      float4 ci = itile[t];
      int a = asym[a2t[ib * TI + t]];
#pragma unroll
      for (int u = 0; u < JSLOTS; ++u) {
        float d = fmaf(ci.x, xj[u], fmaf(ci.y, yj[u], fmaf(ci.z, zj[u], ci.w)));
        if (d > tj2[u]) {
          atomicAdd(&red[a * NC + bj[u]], 1);
          atomicAdd(&red[bj[u] * NC + a], 1);
        }
      }
    }
  }

  __syncthreads();
  if (tid < NC * NC) {
    int v = red[tid];
    if (v) atomicAdd(&counts[s * NC * NC + tid], v);
  }
}

__global__ __launch_bounds__(THREADS)
void finalize_kernel(const int* __restrict__ asym, const int* __restrict__ counts,
                     float* __restrict__ out) {
  __shared__ int hist[NC];
  int tid = threadIdx.x;
  if (tid < NC) hist[tid] = 0;
  __syncthreads();
  for (int t = tid; t < NTOK; t += THREADS) atomicAdd(&hist[asym[t]], NA / NTOK);
  __syncthreads();

  // tid = s*64 + a*8 + b  (256 threads cover all entries)
  int c = counts[tid];
  int a = (tid >> 3) & 7, b = tid & 7;
  float total = (a == b) ? 0.0f : (float)c;
  float minn = (float)min(hist[a], hist[b]);
  float rel = total / minn;
  out[tid] = ((total > 100.0f) || (rel > 0.5f)) ? 1.0f : 0.0f;
  out[256 + 2 * tid + 0] = total;
  out[256 + 2 * tid + 1] = rel;
}

extern "C" void kernel_launch(void* const* d_in, const int* in_sizes, int n_in,
                              void* d_out, int out_size, void* d_ws, size_t ws_size,
                              hipStream_t stream) {
  const float* coords = (const float*)d_in[0];  // [4, 8192, 3] f32
  const int* asym = (const int*)d_in[1];        // [1024] i32
  const int* a2t = (const int*)d_in[2];         // [8192] i32
  float* out = (float*)d_out;                   // 256 flags + 512 details

  int* counts = (int*)d_ws;                     // [NS*NC*NC]

  hipMemsetAsync(counts, 0, NS * NC * NC * sizeof(int), stream);
  clash_kernel<<<dim3(GRIDX, 1, NS), THREADS, 0, stream>>>(coords, asym, a2t, counts);
  finalize_kernel<<<1, THREADS, 0, stream>>>(asym, counts, out);
}